// Round 1
// baseline (120.338 us; speedup 1.0000x reference)
//
#include <hip/hip_runtime.h>

// CSR SpMM, sum aggregation: out[i] = sum_{j in [rowptr[i], rowptr[i+1])} x[col[j]]
// x: [N=50000, D=128] f32, rowptr: [N+1] i32, col: [E=1.6M] i32, out: [N, D] f32.
//
// Layout: 32 lanes per row, each lane holds one float4 (4 feats) -> a full
// 128-float x row is one 512B coalesced gather per edge. 8 rows per 256-thread
// block. Edge loop unrolled 4x for memory-level parallelism.

#define ROWS_PER_BLOCK 8

__device__ __forceinline__ void acc4(float4& a, const float4 b) {
    a.x += b.x; a.y += b.y; a.z += b.z; a.w += b.w;
}

__global__ __launch_bounds__(256) void spmm_csr_kernel(
    const float4* __restrict__ x4,
    const int*    __restrict__ rowptr,
    const int*    __restrict__ col,
    float4*       __restrict__ out4,
    int n_nodes)
{
    const int lane = threadIdx.x & 31;          // which float4 of the row (0..31)
    const int grp  = threadIdx.x >> 5;          // row group within block (0..7)
    const int row  = blockIdx.x * ROWS_PER_BLOCK + grp;
    if (row >= n_nodes) return;

    const int r0 = rowptr[row];
    const int r1 = rowptr[row + 1];

    float4 acc = make_float4(0.f, 0.f, 0.f, 0.f);

    int j = r0;
    // 4x unrolled main loop: 4 independent gathers in flight.
    for (; j + 4 <= r1; j += 4) {
        const int c0 = col[j + 0];
        const int c1 = col[j + 1];
        const int c2 = col[j + 2];
        const int c3 = col[j + 3];
        float4 a = x4[(size_t)c0 * 32 + lane];
        float4 b = x4[(size_t)c1 * 32 + lane];
        float4 c = x4[(size_t)c2 * 32 + lane];
        float4 d = x4[(size_t)c3 * 32 + lane];
        acc4(acc, a); acc4(acc, b); acc4(acc, c); acc4(acc, d);
    }
    for (; j < r1; ++j) {
        const int c = col[j];
        acc4(acc, x4[(size_t)c * 32 + lane]);
    }

    out4[(size_t)row * 32 + lane] = acc;
}

extern "C" void kernel_launch(void* const* d_in, const int* in_sizes, int n_in,
                              void* d_out, int out_size, void* d_ws, size_t ws_size,
                              hipStream_t stream) {
    const float* x      = (const float*)d_in[0];
    const int*   rowptr = (const int*)d_in[1];
    const int*   col    = (const int*)d_in[2];
    float*       out    = (float*)d_out;

    const int n_nodes = in_sizes[1] - 1;

    const int blocks = (n_nodes + ROWS_PER_BLOCK - 1) / ROWS_PER_BLOCK;
    spmm_csr_kernel<<<blocks, 256, 0, stream>>>(
        (const float4*)x, rowptr, col, (float4*)out, n_nodes);
}